// Round 5
// baseline (251.788 us; speedup 1.0000x reference)
//
#include <hip/hip_runtime.h>
#include <hip/hip_cooperative_groups.h>

namespace cg = cooperative_groups;

// Problem constants (match reference)
#define NN    20000
#define EDGES 320000
#define HH    8
#define CC    120
#define HC    960
#define SLOPE 0.2f
#define BUCKET 64      // max in-degree bound (Poisson(16); P(>64) ~ 1e-20)
#define GRID  1250     // GRID*TPB == EDGES exactly; 1250*16 == NN for proj/gather
#define TPB   256

// One cooperative kernel:
//  Phase A: zero cnt; blocks 0..7 build U (col h = W_h@att_src[h], 8+h = W_h@att_dst[h],
//           16+2h / 17+2h = W_h@fc_w[:,j] slice h); block 8 builds cbias.
//           Each thread pre-loads its edge (s,d).
//  sync
//  Phase B: scatter edge -> bucket list; proj P[n][0:32] = x[n]@U (2 tiles of 8 nodes).
//  sync
//  Phase C: gather per dst: softmax-weighted sum of z, 16 lanes/dst, no atomics.
__global__ __launch_bounds__(TPB) void fused_kernel(
    const float* __restrict__ x,
    const int* __restrict__ ei,
    const float* __restrict__ W,
    const float* __restrict__ att_src,
    const float* __restrict__ att_dst,
    const float* __restrict__ bias,
    const float* __restrict__ fc_w,
    const float* __restrict__ fc_b,
    float* __restrict__ U,
    float* __restrict__ cbias,
    unsigned* __restrict__ cnt,
    unsigned* __restrict__ list,
    float* __restrict__ P,
    float* __restrict__ out) {
  cg::grid_group grid = cg::this_grid();
  __shared__ float xs[8 * 128];
  __shared__ float Us[128 * 32];
  int t = threadIdx.x;
  int blk = blockIdx.x;
  int gid = blk * TPB + t;          // 0..319999 == edge id

  // ---------------- Phase A ----------------
  int es = ei[gid];                 // this thread's edge (src, dst)
  int ed = ei[EDGES + gid];
  if (gid < NN) cnt[gid] = 0u;
  if (blk < 8 && t < 128) {
    int h = blk, k = t;
    float a0 = 0.f, a1 = 0.f, a2 = 0.f, a3 = 0.f;
    const float* wrow = W + (size_t)k * HC + h * CC;
#pragma unroll 4
    for (int c = 0; c < CC; ++c) {
      float w = wrow[c];
      a0 = fmaf(w, att_src[h * CC + c], a0);
      a1 = fmaf(w, att_dst[h * CC + c], a1);
      a2 = fmaf(w, fc_w[(h * CC + c) * 2 + 0], a2);
      a3 = fmaf(w, fc_w[(h * CC + c) * 2 + 1], a3);
    }
    U[k * 32 + h]          = a0;
    U[k * 32 + 8 + h]      = a1;
    U[k * 32 + 16 + 2 * h] = a2;
    U[k * 32 + 17 + 2 * h] = a3;
  }
  if (blk == 8 && t < 2) {
    float s2 = fc_b[t];
    for (int i = 0; i < HC; ++i) s2 = fmaf(bias[i], fc_w[i * 2 + t], s2);
    cbias[t] = s2;
  }
  grid.sync();

  // ---------------- Phase B ----------------
  // scatter first: atomic latency hides under the GEMM below
  unsigned slot = atomicAdd(&cnt[ed], 1u);
  list[(size_t)ed * BUCKET + slot] = (unsigned)es;

  for (int i = t; i < 128 * 32; i += TPB) Us[i] = U[i];
#pragma unroll
  for (int half = 0; half < 2; ++half) {
    int n0 = blk * 16 + half * 8;
    for (int i = t; i < 8 * 128; i += TPB) {
      int r = i >> 7, k = i & 127;
      xs[i] = x[(size_t)(n0 + r) * 128 + k];
    }
    __syncthreads();
    int r = t >> 5, c = t & 31;
    float acc = 0.f;
#pragma unroll 8
    for (int k = 0; k < 128; ++k) acc = fmaf(xs[r * 128 + k], Us[k * 32 + c], acc);
    P[(size_t)(n0 + r) * 32 + c] = acc;
    __syncthreads();
  }
  grid.sync();

  // ---------------- Phase C ----------------
  int grp = t >> 4;          // 0..15
  int idx = t & 15;          // lane within group
  int h = idx & 7;           // head
  int half = idx >> 3;       // edge-list half
  int dst = blk * 16 + grp;  // 1250*16 == 20000 exactly

  const float* pd = P + (size_t)dst * 32;
  float ad = pd[8 + h];
  unsigned deg = cnt[dst];
  const unsigned* lp = list + (size_t)dst * BUCKET;

  float accd = 0.f, acc0 = 0.f, acc1 = 0.f;
  if (half == 0) {  // self-loop: src = dst
    float v = pd[h] + ad;
    v = (v > 0.f) ? v : SLOPE * v;
    float ex = __expf(v);
    float2 z = *(const float2*)(pd + 16 + 2 * h);
    accd = ex;
    acc0 = ex * z.x;
    acc1 = ex * z.y;
  }
#pragma unroll 2
  for (unsigned i = half; i < deg; i += 2) {
    int src = (int)lp[i];
    const float* ps = P + (size_t)src * 32;
    float as = ps[h];
    float2 z = *(const float2*)(ps + 16 + 2 * h);
    float v = as + ad;
    v = (v > 0.f) ? v : SLOPE * v;
    float ex = __expf(v);
    accd += ex;
    acc0 = fmaf(ex, z.x, acc0);
    acc1 = fmaf(ex, z.y, acc1);
  }
  float accd_tot = accd + __shfl_xor(accd, 8);
  float r0 = acc0 / accd_tot;
  float r1 = acc1 / accd_tot;
#pragma unroll
  for (int m = 1; m < 16; m <<= 1) {
    r0 += __shfl_xor(r0, m);
    r1 += __shfl_xor(r1, m);
  }
  if (idx == 0) {
    out[(size_t)dst * 2 + 0] = cbias[0] + r0;
    out[(size_t)dst * 2 + 1] = cbias[1] + r1;
  }
}

extern "C" void kernel_launch(void* const* d_in, const int* in_sizes, int n_in,
                              void* d_out, int out_size, void* d_ws, size_t ws_size,
                              hipStream_t stream) {
  const float* x       = (const float*)d_in[0];
  const int*   ei      = (const int*)d_in[1];
  const float* W       = (const float*)d_in[2];
  const float* att_src = (const float*)d_in[3];
  const float* att_dst = (const float*)d_in[4];
  const float* bias    = (const float*)d_in[5];
  const float* fc_w    = (const float*)d_in[6];
  const float* fc_b    = (const float*)d_in[7];
  float* out = (float*)d_out;

  // Workspace layout (4B units):
  // U[4096] | cbias[2]+pad(to 8192) | P[640000] | cnt[20000] | list[20000*64]
  float*    U     = (float*)d_ws;
  float*    cbias = U + 4096;
  float*    P     = U + 8192;
  unsigned* cnt   = (unsigned*)(P + (size_t)NN * 32);
  unsigned* list  = cnt + NN;

  void* args[] = {
    (void*)&x, (void*)&ei, (void*)&W, (void*)&att_src, (void*)&att_dst,
    (void*)&bias, (void*)&fc_w, (void*)&fc_b,
    (void*)&U, (void*)&cbias, (void*)&cnt, (void*)&list, (void*)&P, (void*)&out
  };
  hipLaunchCooperativeKernel((const void*)fused_kernel, dim3(GRID), dim3(TPB),
                             args, 0, stream);
}

// Round 7
// 48.466 us; speedup vs baseline: 5.1951x; 5.1951x over previous
//
#include <hip/hip_runtime.h>

// Problem constants (match reference)
#define NN    20000
#define EDGES 320000
#define HH    8
#define CC    120
#define HC    960
#define SLOPE 0.2f
#define BUCKET 64   // max in-degree bound (Poisson(16); P(>64) ~ 1e-20)

// U column layout (per k row of U[128][32]):  c = 4h+0 -> W_h@att_src[h] (as)
//   c = 4h+1 -> W_h@fc_w[:,0] slice h (z0);  c = 4h+2 -> W_h@fc_w[:,1] (z1)
//   c = 4h+3 -> W_h@att_dst[h] (ad)
// => P row n: [as,z0,z1,ad] x 8 heads; gather reads ONE float4 per (edge,head).

// ---------------------------------------------------------------------------
// K1 prep: grid 257 x 256.
//   blocks 0..255: one wave per (h,k) pair (p = b*4+wave; k=p>>3, h=p&7),
//     lane-coalesced loads of W/att/fc_w slices + butterfly reduce.
//   block 256: waves 0,1 compute cbias[j] = bias@fc_w[:,j] + fc_b[j].
//   All blocks help zero cnt.
// ---------------------------------------------------------------------------
__global__ __launch_bounds__(256) void prep_kernel(const float* __restrict__ W,
                                                   const float* __restrict__ att_src,
                                                   const float* __restrict__ att_dst,
                                                   const float* __restrict__ bias,
                                                   const float* __restrict__ fc_w,
                                                   const float* __restrict__ fc_b,
                                                   float* __restrict__ U,
                                                   float* __restrict__ cbias,
                                                   unsigned* __restrict__ cnt) {
  int t = threadIdx.x, b = blockIdx.x;
  int gid = b * 256 + t;
  if (gid < NN) cnt[gid] = 0u;

  int l = t & 63;
  if (b < 256) {
    int p = b * 4 + (t >> 6);        // 0..1023
    int k = p >> 3, h = p & 7;
    const float* wrow = W + (size_t)k * HC + h * CC;
    const float* asv  = att_src + h * CC;
    const float* adv  = att_dst + h * CC;
    const float2* fv  = (const float2*)fc_w + h * CC;
    bool tail = (l < CC - 64);       // l < 56
    float w0 = wrow[l],            w1 = tail ? wrow[64 + l] : 0.f;
    float s0 = asv[l],             s1 = tail ? asv[64 + l] : 0.f;
    float d0 = adv[l],             d1 = tail ? adv[64 + l] : 0.f;
    float2 f0 = fv[l];
    float2 f1 = tail ? fv[64 + l] : make_float2(0.f, 0.f);
    float a_s = w0 * s0 + w1 * s1;
    float a_d = w0 * d0 + w1 * d1;
    float z0  = w0 * f0.x + w1 * f1.x;
    float z1  = w0 * f0.y + w1 * f1.y;
#pragma unroll
    for (int m = 1; m < 64; m <<= 1) {
      a_s += __shfl_xor(a_s, m);
      a_d += __shfl_xor(a_d, m);
      z0  += __shfl_xor(z0, m);
      z1  += __shfl_xor(z1, m);
    }
    if (l == 0) {
      float* u = U + k * 32 + 4 * h;
      u[0] = a_s; u[1] = z0; u[2] = z1; u[3] = a_d;
    }
  } else if (t < 128) {
    int j = t >> 6;                  // 0 or 1
    float acc = 0.f;
    for (int m = l; m < HC; m += 64) acc = fmaf(bias[m], fc_w[m * 2 + j], acc);
#pragma unroll
    for (int m = 1; m < 64; m <<= 1) acc += __shfl_xor(acc, m);
    if (l == 0) cbias[j] = acc + fc_b[j];
  }
}

// ---------------------------------------------------------------------------
// K2 fused scatter + proj.  Grid 2500 x 256.
//   scatter: thread g handles edge g (<EDGES): bucket by dst (atomic slot).
//   proj: P[n][0:32] = x[n] @ U, 8 nodes per block; xs read as float4.
// ---------------------------------------------------------------------------
__global__ __launch_bounds__(256) void projscatter_kernel(const float* __restrict__ x,
                                                          const float* __restrict__ U,
                                                          const int* __restrict__ ei,
                                                          unsigned* __restrict__ cnt,
                                                          unsigned* __restrict__ list,
                                                          float* __restrict__ P) {
  __shared__ float xs[8 * 128];
  __shared__ float Us[128 * 32];
  int t = threadIdx.x;
  int g = blockIdx.x * 256 + t;

  if (g < EDGES) {
    int s = ei[g];
    int d = ei[EDGES + g];
    unsigned slot = atomicAdd(&cnt[d], 1u);
    list[(size_t)d * BUCKET + slot] = (unsigned)s;
  }

  int n0 = blockIdx.x * 8;
  for (int i = t; i < 128 * 32; i += 256) Us[i] = U[i];
  for (int i = t; i < 8 * 128; i += 256) {
    int r = i >> 7, k = i & 127;
    xs[i] = x[(size_t)(n0 + r) * 128 + k];
  }
  __syncthreads();
  int r = t >> 5, c = t & 31;
  float acc = 0.f;
  const float4* xv = (const float4*)(xs + r * 128);
#pragma unroll 8
  for (int k4 = 0; k4 < 32; ++k4) {
    float4 v = xv[k4];
    acc = fmaf(v.x, Us[(k4 * 4 + 0) * 32 + c], acc);
    acc = fmaf(v.y, Us[(k4 * 4 + 1) * 32 + c], acc);
    acc = fmaf(v.z, Us[(k4 * 4 + 2) * 32 + c], acc);
    acc = fmaf(v.w, Us[(k4 * 4 + 3) * 32 + c], acc);
  }
  P[(size_t)(n0 + r) * 32 + c] = acc;
}

// ---------------------------------------------------------------------------
// K3 gather: 32 lanes per dst (lane = (q,h): head h, edge-list quarter q),
// 8 dst per 256-thread block, grid 2500.  Bucket entries preloaded into 2
// regs/lane; src ids fetched via __shfl.
// CORRECTNESS: the e-loop trip count is GROUP-UNIFORM (iters = ceil(deg/4),
// deg identical across the group's 32 lanes), so every shfl executes with all
// source lanes active; only the load/accumulate is predicated on e < deg.
// (Divergent-trip-count shfl reads from exited lanes = undefined — R6 bug.)
// Softmax without max-shift (logits bounded ~|9|, fp32-safe).  No atomics.
// ---------------------------------------------------------------------------
__global__ __launch_bounds__(256) void gather_kernel(const unsigned* __restrict__ cnt,
                                                     const unsigned* __restrict__ list,
                                                     const float* __restrict__ P,
                                                     const float* __restrict__ cbias,
                                                     float* __restrict__ out) {
  int t = threadIdx.x;
  int grp = t >> 5;            // 0..7 : dst group in block
  int idx = t & 31;            // lane in group
  int h = idx & 7;             // head
  int q = idx >> 3;            // quarter
  int base = (t & 63) & ~31;   // group start lane within wave (0 or 32)
  int dst = blockIdx.x * 8 + grp;   // 2500*8 == 20000 exactly

  const float* pd = P + (size_t)dst * 32;
  float4 pd4 = *(const float4*)(pd + 4 * h);   // as,z0,z1,ad of dst
  float ad = pd4.w;
  unsigned deg = cnt[dst];
  const unsigned* lp = list + (size_t)dst * BUCKET;
  unsigned r0v = lp[idx];          // bucket slots 0..31
  unsigned r1v = lp[idx + 32];     // bucket slots 32..63 (unused if deg<=32)

  float accd = 0.f, acc0 = 0.f, acc1 = 0.f;
  if (q == 0) {   // self-loop: src = dst
    float v = pd4.x + ad;
    v = (v > 0.f) ? v : SLOPE * v;
    float ex = __expf(v);
    accd = ex;
    acc0 = ex * pd4.y;
    acc1 = ex * pd4.z;
  }
  unsigned iters = (deg + 3u) >> 2;     // group-uniform
  unsigned e = (unsigned)q;
  for (unsigned i = 0; i < iters; ++i, e += 4u) {
    int lane = base + (int)(e & 31u);
    unsigned s0 = __shfl(r0v, lane);    // all group lanes active here
    unsigned s1 = __shfl(r1v, lane);
    unsigned src = (e < 32u) ? s0 : s1;
    if (e < deg) {
      float4 ps4 = *(const float4*)(P + (size_t)src * 32 + 4 * h);
      float v = ps4.x + ad;
      v = (v > 0.f) ? v : SLOPE * v;
      float ex = __expf(v);
      accd += ex;
      acc0 = fmaf(ex, ps4.y, acc0);
      acc1 = fmaf(ex, ps4.z, acc1);
    }
  }
  // per-head denominator: sum accd over the 4 quarters (xor 8, 16)
  float accd_tot = accd + __shfl_xor(accd, 8);
  accd_tot += __shfl_xor(accd_tot, 16);
  float r0 = acc0 / accd_tot;
  float r1 = acc1 / accd_tot;
#pragma unroll
  for (int m = 1; m < 32; m <<= 1) {
    r0 += __shfl_xor(r0, m);
    r1 += __shfl_xor(r1, m);
  }
  if (idx == 0) {
    out[(size_t)dst * 2 + 0] = cbias[0] + r0;
    out[(size_t)dst * 2 + 1] = cbias[1] + r1;
  }
}

extern "C" void kernel_launch(void* const* d_in, const int* in_sizes, int n_in,
                              void* d_out, int out_size, void* d_ws, size_t ws_size,
                              hipStream_t stream) {
  const float* x       = (const float*)d_in[0];
  const int*   ei      = (const int*)d_in[1];
  const float* W       = (const float*)d_in[2];
  const float* att_src = (const float*)d_in[3];
  const float* att_dst = (const float*)d_in[4];
  const float* bias    = (const float*)d_in[5];
  const float* fc_w    = (const float*)d_in[6];
  const float* fc_b    = (const float*)d_in[7];
  float* out = (float*)d_out;

  // Workspace layout (4B units):
  // U[4096] | cbias[2]+pad(to 8192) | P[640000] | cnt[20000] | list[20000*64]
  float*    U     = (float*)d_ws;
  float*    cbias = U + 4096;
  float*    P     = U + 8192;
  unsigned* cnt   = (unsigned*)(P + (size_t)NN * 32);
  unsigned* list  = cnt + NN;

  prep_kernel<<<257, 256, 0, stream>>>(W, att_src, att_dst, bias, fc_w, fc_b, U, cbias, cnt);
  projscatter_kernel<<<NN / 8, 256, 0, stream>>>(x, U, ei, cnt, list, P);
  gather_kernel<<<NN / 8, 256, 0, stream>>>(cnt, list, P, cbias, out);
}

// Round 8
// 44.003 us; speedup vs baseline: 5.7220x; 1.1014x over previous
//
#include <hip/hip_runtime.h>

// Problem constants (match reference)
#define NN    20000
#define EDGES 320000
#define HH    8
#define CC    120
#define HC    960
#define SLOPE 0.2f
#define BUCKET 64   // max in-degree bound (Poisson(16); P(>64) ~ 1e-20)

// U column layout (per k row of U[128][32]):  c = 4h+0 -> W_h@att_src[h] (as)
//   c = 4h+1 -> W_h@fc_w[:,0] slice h (z0);  c = 4h+2 -> W_h@fc_w[:,1] (z1)
//   c = 4h+3 -> W_h@att_dst[h] (ad)
// => P row n: [as,z0,z1,ad] x 8 heads; gather reads ONE float4 per (edge,head).

// ---------------------------------------------------------------------------
// K1 prep: grid 257 x 256.
//   blocks 0..255: one wave per (h,k) pair (p = b*4+wave; k=p>>3, h=p&7),
//     lane-coalesced loads of W/att/fc_w slices + butterfly reduce.
//   block 256: waves 0,1 compute cbias[j] = bias@fc_w[:,j] + fc_b[j].
//   All blocks help zero cnt.
// ---------------------------------------------------------------------------
__global__ __launch_bounds__(256) void prep_kernel(const float* __restrict__ W,
                                                   const float* __restrict__ att_src,
                                                   const float* __restrict__ att_dst,
                                                   const float* __restrict__ bias,
                                                   const float* __restrict__ fc_w,
                                                   const float* __restrict__ fc_b,
                                                   float* __restrict__ U,
                                                   float* __restrict__ cbias,
                                                   unsigned* __restrict__ cnt) {
  int t = threadIdx.x, b = blockIdx.x;
  int gid = b * 256 + t;
  if (gid < NN) cnt[gid] = 0u;

  int l = t & 63;
  if (b < 256) {
    int p = b * 4 + (t >> 6);        // 0..1023
    int k = p >> 3, h = p & 7;
    const float* wrow = W + (size_t)k * HC + h * CC;
    const float* asv  = att_src + h * CC;
    const float* adv  = att_dst + h * CC;
    const float2* fv  = (const float2*)fc_w + h * CC;
    bool tail = (l < CC - 64);       // l < 56
    float w0 = wrow[l],            w1 = tail ? wrow[64 + l] : 0.f;
    float s0 = asv[l],             s1 = tail ? asv[64 + l] : 0.f;
    float d0 = adv[l],             d1 = tail ? adv[64 + l] : 0.f;
    float2 f0 = fv[l];
    float2 f1 = tail ? fv[64 + l] : make_float2(0.f, 0.f);
    float a_s = w0 * s0 + w1 * s1;
    float a_d = w0 * d0 + w1 * d1;
    float z0  = w0 * f0.x + w1 * f1.x;
    float z1  = w0 * f0.y + w1 * f1.y;
#pragma unroll
    for (int m = 1; m < 64; m <<= 1) {
      a_s += __shfl_xor(a_s, m);
      a_d += __shfl_xor(a_d, m);
      z0  += __shfl_xor(z0, m);
      z1  += __shfl_xor(z1, m);
    }
    if (l == 0) {
      float* u = U + k * 32 + 4 * h;
      u[0] = a_s; u[1] = z0; u[2] = z1; u[3] = a_d;
    }
  } else if (t < 128) {
    int j = t >> 6;                  // 0 or 1
    float acc = 0.f;
    for (int m = l; m < HC; m += 64) acc = fmaf(bias[m], fc_w[m * 2 + j], acc);
#pragma unroll
    for (int m = 1; m < 64; m <<= 1) acc += __shfl_xor(acc, m);
    if (l == 0) cbias[j] = acc + fc_b[j];
  }
}

// ---------------------------------------------------------------------------
// K2 fused scatter + proj.  Grid 2500 x 256.
//   scatter: thread g handles edge g (<EDGES): bucket by dst (atomic slot).
//   proj: P[n][0:32] = x[n] @ U, 8 nodes per block.
//   All staging is float4 (dwordx4 + ds_write_b128); staging loads issue
//   independently of the atomic so its round-trip hides under them.
// ---------------------------------------------------------------------------
__global__ __launch_bounds__(256) void projscatter_kernel(const float* __restrict__ x,
                                                          const float* __restrict__ U,
                                                          const int* __restrict__ ei,
                                                          unsigned* __restrict__ cnt,
                                                          unsigned* __restrict__ list,
                                                          float* __restrict__ P) {
  __shared__ float4 xs4[256];      // 8 rows x 128 floats
  __shared__ float4 Us4[1024];     // 128 x 32 floats
  int t = threadIdx.x;
  int g = blockIdx.x * 256 + t;
  int n0 = blockIdx.x * 8;

  // issue staging loads (independent of the atomic below)
  float4 xv  = ((const float4*)(x + (size_t)n0 * 128))[t];
  const float4* U4 = (const float4*)U;
  float4 uv0 = U4[t];
  float4 uv1 = U4[t + 256];
  float4 uv2 = U4[t + 512];
  float4 uv3 = U4[t + 768];

  if (g < EDGES) {
    int s = ei[g];
    int d = ei[EDGES + g];
    unsigned slot = atomicAdd(&cnt[d], 1u);
    list[(size_t)d * BUCKET + slot] = (unsigned)s;
  }

  xs4[t] = xv;
  Us4[t] = uv0; Us4[t + 256] = uv1; Us4[t + 512] = uv2; Us4[t + 768] = uv3;
  __syncthreads();

  int r = t >> 5, c = t & 31;
  float acc = 0.f;
  const float4* xrow = xs4 + r * 32;
  const float* Us = (const float*)Us4;
#pragma unroll 8
  for (int k4 = 0; k4 < 32; ++k4) {
    float4 v = xrow[k4];
    acc = fmaf(v.x, Us[(k4 * 4 + 0) * 32 + c], acc);
    acc = fmaf(v.y, Us[(k4 * 4 + 1) * 32 + c], acc);
    acc = fmaf(v.z, Us[(k4 * 4 + 2) * 32 + c], acc);
    acc = fmaf(v.w, Us[(k4 * 4 + 3) * 32 + c], acc);
  }
  P[(size_t)(n0 + r) * 32 + c] = acc;
}

// ---------------------------------------------------------------------------
// K3 gather: ONE WAVE (64 lanes) per dst: lane = (o,h), head h = lane&7,
// octant o = lane>>3.  4 dst per 256-thread block, grid 5000.
// Bucket (<=64 slots) preloaded into ONE reg/lane; src ids via __shfl.
// Trip count is WAVE-UNIFORM (deg same for all 64 lanes) so every shfl
// executes with all source lanes active; load/accum predicated on e < deg.
// Softmax without max-shift (logits bounded ~|9|, fp32-safe).  No atomics.
// ---------------------------------------------------------------------------
__global__ __launch_bounds__(256) void gather_kernel(const unsigned* __restrict__ cnt,
                                                     const unsigned* __restrict__ list,
                                                     const float* __restrict__ P,
                                                     const float* __restrict__ cbias,
                                                     float* __restrict__ out) {
  int t = threadIdx.x;
  int wave = t >> 6;           // 0..3
  int lane = t & 63;
  int h = lane & 7;            // head
  int o = lane >> 3;           // octant (edge-list 8-way split)
  int dst = blockIdx.x * 4 + wave;   // 5000*4 == 20000 exactly

  const float* pd = P + (size_t)dst * 32;
  float4 pd4 = *(const float4*)(pd + 4 * h);   // as,z0,z1,ad of dst
  float ad = pd4.w;
  unsigned deg = cnt[dst];
  unsigned rv = list[(size_t)dst * BUCKET + lane];  // slot `lane` of bucket

  float accd = 0.f, acc0 = 0.f, acc1 = 0.f;
  if (o == 0) {   // self-loop: src = dst
    float v = pd4.x + ad;
    v = (v > 0.f) ? v : SLOPE * v;
    float ex = __expf(v);
    accd = ex;
    acc0 = ex * pd4.y;
    acc1 = ex * pd4.z;
  }
  unsigned iters = (deg + 7u) >> 3;     // wave-uniform
  unsigned e = (unsigned)o;
  for (unsigned i = 0; i < iters; ++i, e += 8u) {
    unsigned src = __shfl(rv, (int)e);  // all 64 lanes active here
    if (e < deg) {
      float4 ps4 = *(const float4*)(P + (size_t)src * 32 + 4 * h);
      float v = ps4.x + ad;
      v = (v > 0.f) ? v : SLOPE * v;
      float ex = __expf(v);
      accd += ex;
      acc0 = fmaf(ex, ps4.y, acc0);
      acc1 = fmaf(ex, ps4.z, acc1);
    }
  }
  // per-head denominator: sum accd over the 8 octants (xor 8,16,32)
  float accd_tot = accd + __shfl_xor(accd, 8);
  accd_tot += __shfl_xor(accd_tot, 16);
  accd_tot += __shfl_xor(accd_tot, 32);
  float r0 = acc0 / accd_tot;
  float r1 = acc1 / accd_tot;
#pragma unroll
  for (int m = 1; m < 64; m <<= 1) {
    r0 += __shfl_xor(r0, m);
    r1 += __shfl_xor(r1, m);
  }
  if (lane == 0) {
    ((float2*)out)[dst] = make_float2(cbias[0] + r0, cbias[1] + r1);
  }
}

extern "C" void kernel_launch(void* const* d_in, const int* in_sizes, int n_in,
                              void* d_out, int out_size, void* d_ws, size_t ws_size,
                              hipStream_t stream) {
  const float* x       = (const float*)d_in[0];
  const int*   ei      = (const int*)d_in[1];
  const float* W       = (const float*)d_in[2];
  const float* att_src = (const float*)d_in[3];
  const float* att_dst = (const float*)d_in[4];
  const float* bias    = (const float*)d_in[5];
  const float* fc_w    = (const float*)d_in[6];
  const float* fc_b    = (const float*)d_in[7];
  float* out = (float*)d_out;

  // Workspace layout (4B units):
  // U[4096] | cbias[2]+pad(to 8192) | P[640000] | cnt[20000] | list[20000*64]
  float*    U     = (float*)d_ws;
  float*    cbias = U + 4096;
  float*    P     = U + 8192;
  unsigned* cnt   = (unsigned*)(P + (size_t)NN * 32);
  unsigned* list  = cnt + NN;

  prep_kernel<<<257, 256, 0, stream>>>(W, att_src, att_dst, bias, fc_w, fc_b, U, cbias, cnt);
  projscatter_kernel<<<NN / 8, 256, 0, stream>>>(x, U, ei, cnt, list, P);
  gather_kernel<<<NN / 4, 256, 0, stream>>>(cnt, list, P, cbias, out);
}

// Round 9
// 41.563 us; speedup vs baseline: 6.0580x; 1.0587x over previous
//
#include <hip/hip_runtime.h>

// Problem constants (match reference)
#define NN    20000
#define EDGES 320000
#define HH    8
#define CC    120
#define HC    960
#define SLOPE 0.2f
#define BUCKET 64   // max in-degree bound (Poisson(16); P(>64) ~ 1e-20)

// U column layout (per k row of U[128][32]):  c = 4h+0 -> W_h@att_src[h] (as)
//   c = 4h+1 -> W_h@fc_w[:,0] slice h (z0);  c = 4h+2 -> W_h@fc_w[:,1] (z1)
//   c = 4h+3 -> W_h@att_dst[h] (ad)
// => P row n: [as,z0,z1,ad] x 8 heads; gather reads ONE float4 per (edge,head).

// ---------------------------------------------------------------------------
// K1 prep: grid 257 x 256.
//   blocks 0..255: one wave per (h,k) pair (p = b*4+wave; k=p>>3, h=p&7),
//     lane-coalesced loads of W/att/fc_w slices + butterfly reduce.
//   block 256: waves 0,1 compute cbias[j] = bias@fc_w[:,j] + fc_b[j].
//   All blocks help zero cnt.
// ---------------------------------------------------------------------------
__global__ __launch_bounds__(256) void prep_kernel(const float* __restrict__ W,
                                                   const float* __restrict__ att_src,
                                                   const float* __restrict__ att_dst,
                                                   const float* __restrict__ bias,
                                                   const float* __restrict__ fc_w,
                                                   const float* __restrict__ fc_b,
                                                   float* __restrict__ U,
                                                   float* __restrict__ cbias,
                                                   unsigned* __restrict__ cnt) {
  int t = threadIdx.x, b = blockIdx.x;
  int gid = b * 256 + t;
  if (gid < NN) cnt[gid] = 0u;

  int l = t & 63;
  if (b < 256) {
    int p = b * 4 + (t >> 6);        // 0..1023
    int k = p >> 3, h = p & 7;
    const float* wrow = W + (size_t)k * HC + h * CC;
    const float* asv  = att_src + h * CC;
    const float* adv  = att_dst + h * CC;
    const float2* fv  = (const float2*)fc_w + h * CC;
    bool tail = (l < CC - 64);       // l < 56
    float w0 = wrow[l],            w1 = tail ? wrow[64 + l] : 0.f;
    float s0 = asv[l],             s1 = tail ? asv[64 + l] : 0.f;
    float d0 = adv[l],             d1 = tail ? adv[64 + l] : 0.f;
    float2 f0 = fv[l];
    float2 f1 = tail ? fv[64 + l] : make_float2(0.f, 0.f);
    float a_s = w0 * s0 + w1 * s1;
    float a_d = w0 * d0 + w1 * d1;
    float z0  = w0 * f0.x + w1 * f1.x;
    float z1  = w0 * f0.y + w1 * f1.y;
#pragma unroll
    for (int m = 1; m < 64; m <<= 1) {
      a_s += __shfl_xor(a_s, m);
      a_d += __shfl_xor(a_d, m);
      z0  += __shfl_xor(z0, m);
      z1  += __shfl_xor(z1, m);
    }
    if (l == 0) {
      float* u = U + k * 32 + 4 * h;
      u[0] = a_s; u[1] = z0; u[2] = z1; u[3] = a_d;
    }
  } else if (t < 128) {
    int j = t >> 6;                  // 0 or 1
    float acc = 0.f;
    for (int m = l; m < HC; m += 64) acc = fmaf(bias[m], fc_w[m * 2 + j], acc);
#pragma unroll
    for (int m = 1; m < 64; m <<= 1) acc += __shfl_xor(acc, m);
    if (l == 0) cbias[j] = acc + fc_b[j];
  }
}

// ---------------------------------------------------------------------------
// K2 fused scatter + proj.  Grid 625 x 256, 32 nodes + 512 edges per block.
//   scatter: thread t handles edges b*512+t and b*512+t+256.
//   proj: each thread computes a 1x4 output strip (row r = t>>3, cols
//   4cq..4cq+3, cq = t&7): 160 LDS instr / 4 outputs (was 160/1).
//   xs stride 132 (pad 4): r-groups hit disjoint bank quads; Us reads span
//   all 32 banks with 8-way broadcast -> both conflict-free.
// ---------------------------------------------------------------------------
#define XSTR 132
__global__ __launch_bounds__(256) void projscatter_kernel(const float* __restrict__ x,
                                                          const float* __restrict__ U,
                                                          const int* __restrict__ ei,
                                                          unsigned* __restrict__ cnt,
                                                          unsigned* __restrict__ list,
                                                          float* __restrict__ P) {
  __shared__ float xs[32 * XSTR];    // 32 rows x 128 (+4 pad)
  __shared__ float Us[128 * 32];
  int t = threadIdx.x;
  int b = blockIdx.x;
  int n0 = b * 32;

  // issue staging loads (independent of the atomics below)
  const float4* xg = (const float4*)(x + (size_t)n0 * 128);
  float4 xv0 = xg[t], xv1 = xg[t + 256], xv2 = xg[t + 512], xv3 = xg[t + 768];
  const float4* U4 = (const float4*)U;
  float4 uv0 = U4[t], uv1 = U4[t + 256], uv2 = U4[t + 512], uv3 = U4[t + 768];

  // scatter: 2 edges per thread
  int g0 = b * 512 + t;
  {
    int s0 = ei[g0],        d0 = ei[EDGES + g0];
    int s1 = ei[g0 + 256],  d1 = ei[EDGES + g0 + 256];
    unsigned slot0 = atomicAdd(&cnt[d0], 1u);
    unsigned slot1 = atomicAdd(&cnt[d1], 1u);
    list[(size_t)d0 * BUCKET + slot0] = (unsigned)s0;
    list[(size_t)d1 * BUCKET + slot1] = (unsigned)s1;
  }

  // place staged data (float4 i -> row i>>5, quad i&31)
  {
    int i0 = t, i1 = t + 256, i2 = t + 512, i3 = t + 768;
    *(float4*)(xs + (i0 >> 5) * XSTR + (i0 & 31) * 4) = xv0;
    *(float4*)(xs + (i1 >> 5) * XSTR + (i1 & 31) * 4) = xv1;
    *(float4*)(xs + (i2 >> 5) * XSTR + (i2 & 31) * 4) = xv2;
    *(float4*)(xs + (i3 >> 5) * XSTR + (i3 & 31) * 4) = xv3;
    ((float4*)Us)[t] = uv0; ((float4*)Us)[t + 256] = uv1;
    ((float4*)Us)[t + 512] = uv2; ((float4*)Us)[t + 768] = uv3;
  }
  __syncthreads();

  int r = t >> 3, cq = t & 7;        // row, col-quad
  float a0 = 0.f, a1 = 0.f, a2 = 0.f, a3 = 0.f;
  const float* xrow = xs + r * XSTR;
#pragma unroll 4
  for (int k4 = 0; k4 < 32; ++k4) {
    float4 xv = *(const float4*)(xrow + k4 * 4);
    float4 u0 = *(const float4*)(Us + (k4 * 4 + 0) * 32 + 4 * cq);
    float4 u1 = *(const float4*)(Us + (k4 * 4 + 1) * 32 + 4 * cq);
    float4 u2 = *(const float4*)(Us + (k4 * 4 + 2) * 32 + 4 * cq);
    float4 u3 = *(const float4*)(Us + (k4 * 4 + 3) * 32 + 4 * cq);
    a0 = fmaf(xv.x, u0.x, a0); a1 = fmaf(xv.x, u0.y, a1);
    a2 = fmaf(xv.x, u0.z, a2); a3 = fmaf(xv.x, u0.w, a3);
    a0 = fmaf(xv.y, u1.x, a0); a1 = fmaf(xv.y, u1.y, a1);
    a2 = fmaf(xv.y, u1.z, a2); a3 = fmaf(xv.y, u1.w, a3);
    a0 = fmaf(xv.z, u2.x, a0); a1 = fmaf(xv.z, u2.y, a1);
    a2 = fmaf(xv.z, u2.z, a2); a3 = fmaf(xv.z, u2.w, a3);
    a0 = fmaf(xv.w, u3.x, a0); a1 = fmaf(xv.w, u3.y, a1);
    a2 = fmaf(xv.w, u3.z, a2); a3 = fmaf(xv.w, u3.w, a3);
  }
  *(float4*)(P + (size_t)(n0 + r) * 32 + 4 * cq) = make_float4(a0, a1, a2, a3);
}

// ---------------------------------------------------------------------------
// K3 gather: ONE WAVE (64 lanes) per dst: lane = (o,h), head h = lane&7,
// octant o = lane>>3.  4 dst per 256-thread block, grid 5000.
// Bucket (<=64 slots) preloaded into ONE reg/lane; src ids via __shfl.
// Trip count is WAVE-UNIFORM (deg same for all 64 lanes) so every shfl
// executes with all source lanes active; load/accum predicated on e < deg.
// Softmax without max-shift (logits bounded ~|9|, fp32-safe).  No atomics.
// ---------------------------------------------------------------------------
__global__ __launch_bounds__(256) void gather_kernel(const unsigned* __restrict__ cnt,
                                                     const unsigned* __restrict__ list,
                                                     const float* __restrict__ P,
                                                     const float* __restrict__ cbias,
                                                     float* __restrict__ out) {
  int t = threadIdx.x;
  int wave = t >> 6;           // 0..3
  int lane = t & 63;
  int h = lane & 7;            // head
  int o = lane >> 3;           // octant (edge-list 8-way split)
  int dst = blockIdx.x * 4 + wave;   // 5000*4 == 20000 exactly

  const float* pd = P + (size_t)dst * 32;
  float4 pd4 = *(const float4*)(pd + 4 * h);   // as,z0,z1,ad of dst
  float ad = pd4.w;
  unsigned deg = cnt[dst];
  unsigned rv = list[(size_t)dst * BUCKET + lane];  // slot `lane` of bucket

  float accd = 0.f, acc0 = 0.f, acc1 = 0.f;
  if (o == 0) {   // self-loop: src = dst
    float v = pd4.x + ad;
    v = (v > 0.f) ? v : SLOPE * v;
    float ex = __expf(v);
    accd = ex;
    acc0 = ex * pd4.y;
    acc1 = ex * pd4.z;
  }
  unsigned iters = (deg + 7u) >> 3;     // wave-uniform
  unsigned e = (unsigned)o;
  for (unsigned i = 0; i < iters; ++i, e += 8u) {
    unsigned src = __shfl(rv, (int)e);  // all 64 lanes active here
    if (e < deg) {
      float4 ps4 = *(const float4*)(P + (size_t)src * 32 + 4 * h);
      float v = ps4.x + ad;
      v = (v > 0.f) ? v : SLOPE * v;
      float ex = __expf(v);
      accd += ex;
      acc0 = fmaf(ex, ps4.y, acc0);
      acc1 = fmaf(ex, ps4.z, acc1);
    }
  }
  // per-head denominator: sum accd over the 8 octants (xor 8,16,32)
  float accd_tot = accd + __shfl_xor(accd, 8);
  accd_tot += __shfl_xor(accd_tot, 16);
  accd_tot += __shfl_xor(accd_tot, 32);
  float rcp = 1.0f / accd_tot;
  float r0 = acc0 * rcp;
  float r1 = acc1 * rcp;
#pragma unroll
  for (int m = 1; m < 64; m <<= 1) {
    r0 += __shfl_xor(r0, m);
    r1 += __shfl_xor(r1, m);
  }
  if (lane == 0) {
    ((float2*)out)[dst] = make_float2(cbias[0] + r0, cbias[1] + r1);
  }
}

extern "C" void kernel_launch(void* const* d_in, const int* in_sizes, int n_in,
                              void* d_out, int out_size, void* d_ws, size_t ws_size,
                              hipStream_t stream) {
  const float* x       = (const float*)d_in[0];
  const int*   ei      = (const int*)d_in[1];
  const float* W       = (const float*)d_in[2];
  const float* att_src = (const float*)d_in[3];
  const float* att_dst = (const float*)d_in[4];
  const float* bias    = (const float*)d_in[5];
  const float* fc_w    = (const float*)d_in[6];
  const float* fc_b    = (const float*)d_in[7];
  float* out = (float*)d_out;

  // Workspace layout (4B units):
  // U[4096] | cbias[2]+pad(to 8192) | P[640000] | cnt[20000] | list[20000*64]
  float*    U     = (float*)d_ws;
  float*    cbias = U + 4096;
  float*    P     = U + 8192;
  unsigned* cnt   = (unsigned*)(P + (size_t)NN * 32);
  unsigned* list  = cnt + NN;

  prep_kernel<<<257, 256, 0, stream>>>(W, att_src, att_dst, bias, fc_w, fc_b, U, cbias, cnt);
  projscatter_kernel<<<NN / 32, 256, 0, stream>>>(x, U, ei, cnt, list, P);
  gather_kernel<<<NN / 4, 256, 0, stream>>>(cnt, list, P, cbias, out);
}